// Round 1
// baseline (157.033 us; speedup 1.0000x reference)
//
#include <hip/hip_runtime.h>
#include <hip/hip_bf16.h>
#include <math.h>

// Problem constants (B=4096 rows, D=768 features)
#define B_ROWS 4096
#define D_DIM  768

#define BM 128
#define BN 128
#define BK 64
#define LDT 72   // LDS row stride in bf16 elems: 64 + 8 pad (keeps 16B align, breaks bank-0 stride)

typedef __attribute__((ext_vector_type(8))) short bf16x8;  // 8 bf16 = 4 VGPRs (MFMA A/B frag)
typedef __attribute__((ext_vector_type(4))) float f32x4;   // MFMA C/D frag

__device__ __forceinline__ unsigned short f32_to_bf16(float x) {
    // round-to-nearest-even; inputs are finite normals (no NaN handling needed)
    unsigned int u = __float_as_uint(x);
    return (unsigned short)((u + 0x7fffu + ((u >> 16) & 1u)) >> 16);
}

// K1: per-row stats. One block per row.
//   p_sq[i] = sum p^2 ; t_sq[i] = sum t^2 ; diagl[i] = exact fp32 diagonal logit
//   magr[i] = sum|p-t| / sum|t|
__global__ void __launch_bounds__(256) rowstats_kernel(
    const float* __restrict__ P, const float* __restrict__ T,
    float* __restrict__ p_sq, float* __restrict__ t_sq,
    float* __restrict__ diagl, float* __restrict__ magr)
{
    const int i = blockIdx.x;
    const int tid = threadIdx.x;
    const float* prow = P + (size_t)i * D_DIM;
    const float* trow = T + (size_t)i * D_DIM;
    float psq = 0.f, tsq = 0.f, cr = 0.f, l1 = 0.f, tm = 0.f;
    for (int c = tid; c < D_DIM; c += 256) {
        float p = prow[c], t = trow[c];
        psq += p * p; tsq += t * t; cr += p * t;
        l1 += fabsf(p - t); tm += fabsf(t);
    }
    for (int m = 1; m < 64; m <<= 1) {
        psq += __shfl_xor(psq, m, 64);
        tsq += __shfl_xor(tsq, m, 64);
        cr  += __shfl_xor(cr,  m, 64);
        l1  += __shfl_xor(l1,  m, 64);
        tm  += __shfl_xor(tm,  m, 64);
    }
    __shared__ float red[4][5];
    const int wave = tid >> 6, lane = tid & 63;
    if (lane == 0) {
        red[wave][0] = psq; red[wave][1] = tsq; red[wave][2] = cr;
        red[wave][3] = l1;  red[wave][4] = tm;
    }
    __syncthreads();
    if (tid == 0) {
        psq = red[0][0] + red[1][0] + red[2][0] + red[3][0];
        tsq = red[0][1] + red[1][1] + red[2][1] + red[3][1];
        cr  = red[0][2] + red[1][2] + red[2][2] + red[3][2];
        l1  = red[0][3] + red[1][3] + red[2][3] + red[3][3];
        tm  = red[0][4] + red[1][4] + red[2][4] + red[3][4];
        p_sq[i] = psq;
        t_sq[i] = tsq;
        float sq = fmaxf(psq + tsq - 2.0f * cr, 0.0f);
        diagl[i] = -sqrtf(sq) * 10.0f;   // logit_ii = -dist/0.1, exact fp32 (the LSE shift)
        magr[i]  = l1 / tm;
    }
}

// K2: fused bf16-MFMA cross GEMM + shifted exp row-sum.
// Block computes a 128x128 tile of logits; accumulates per-row
// sum_j exp(logit_ij - logit_ii) in double via atomicAdd.
__global__ void __launch_bounds__(256) lse_gemm_kernel(
    const float* __restrict__ P, const float* __restrict__ T,
    const float* __restrict__ p_sq, const float* __restrict__ t_sq,
    const float* __restrict__ diagl, double* __restrict__ rowsum)
{
    __shared__ unsigned short As[BM * LDT];
    __shared__ unsigned short Bs[BN * LDT];

    const int tid = threadIdx.x;
    const int i0 = blockIdx.y * BM;   // P row block
    const int j0 = blockIdx.x * BN;   // T row block (= logit column block)

    const int lane  = tid & 63;
    const int wave  = tid >> 6;
    const int wm    = wave >> 1, wn = wave & 1;    // 2x2 wave grid
    const int row16 = lane & 15, quad = lane >> 4;
    const int m_base = wm * 64, n_base = wn * 64;

    f32x4 acc[4][4];
    #pragma unroll
    for (int a = 0; a < 4; ++a)
        #pragma unroll
        for (int b = 0; b < 4; ++b)
            acc[a][b] = (f32x4){0.f, 0.f, 0.f, 0.f};

    for (int kt = 0; kt < D_DIM; kt += BK) {
        // Stage both tiles: 128 rows x 64 cols fp32 -> bf16.  2048 float4 per tile.
        #pragma unroll
        for (int it = 0; it < 8; ++it) {
            int idx = it * 256 + tid;
            int r   = idx >> 4;             // 0..127
            int c4  = (idx & 15) << 2;      // 0,4,...,60
            f32x4 pv = *(const f32x4*)(P + (size_t)(i0 + r) * D_DIM + kt + c4);
            f32x4 tv = *(const f32x4*)(T + (size_t)(j0 + r) * D_DIM + kt + c4);
            ushort4 pb = make_ushort4(f32_to_bf16(pv[0]), f32_to_bf16(pv[1]),
                                      f32_to_bf16(pv[2]), f32_to_bf16(pv[3]));
            ushort4 tb = make_ushort4(f32_to_bf16(tv[0]), f32_to_bf16(tv[1]),
                                      f32_to_bf16(tv[2]), f32_to_bf16(tv[3]));
            *(ushort4*)&As[r * LDT + c4] = pb;
            *(ushort4*)&Bs[r * LDT + c4] = tb;
        }
        __syncthreads();

        #pragma unroll
        for (int ks = 0; ks < BK; ks += 32) {
            bf16x8 a[4], b[4];
            #pragma unroll
            for (int mt = 0; mt < 4; ++mt)
                a[mt] = *(const bf16x8*)&As[(m_base + mt * 16 + row16) * LDT + ks + quad * 8];
            #pragma unroll
            for (int nt = 0; nt < 4; ++nt)
                b[nt] = *(const bf16x8*)&Bs[(n_base + nt * 16 + row16) * LDT + ks + quad * 8];
            #pragma unroll
            for (int mt = 0; mt < 4; ++mt)
                #pragma unroll
                for (int nt = 0; nt < 4; ++nt)
                    acc[mt][nt] = __builtin_amdgcn_mfma_f32_16x16x32_bf16(
                        a[mt], b[nt], acc[mt][nt], 0, 0, 0);
        }
        __syncthreads();
    }

    // Epilogue: C/D layout col=lane&15, row=quad*4+reg (m89/m91-verified).
    const float LOG2E = 1.44269504088896340736f;
    #pragma unroll
    for (int mt = 0; mt < 4; ++mt) {
        #pragma unroll
        for (int r = 0; r < 4; ++r) {
            const int i = i0 + m_base + mt * 16 + quad * 4 + r;
            const float psq = p_sq[i];
            const float dlg = diagl[i];
            double s = 0.0;
            #pragma unroll
            for (int nt = 0; nt < 4; ++nt) {
                const int j = j0 + n_base + nt * 16 + row16;
                float c  = acc[mt][nt][r];
                float sq = fmaxf(psq + t_sq[j] - 2.0f * c, 0.0f);
                float logit = -sqrtf(sq) * 10.0f;          // -dist/TEMPERATURE
                float y  = (logit - dlg) * LOG2E;          // shifted, in log2 domain
                float nn = rintf(y);
                float v  = exp2f(y - nn);                  // in [~0.707, ~1.414]
                s += ldexp((double)v, (int)nn);            // exact 2^nn scale in double
            }
            // reduce across the 16 lanes (same quad) that hold this row's columns
            #pragma unroll
            for (int m = 1; m < 16; m <<= 1) s += __shfl_xor(s, m, 64);
            if (row16 == 0) atomicAdd(&rowsum[i], s);
        }
    }
}

// K3: final reduction to the 3 output scalars.
__global__ void __launch_bounds__(256) finalize_kernel(
    const double* __restrict__ rowsum, const float* __restrict__ magr,
    float* __restrict__ out)
{
    const int tid = threadIdx.x;
    double sc = 0.0, sm = 0.0;
    for (int i = tid; i < B_ROWS; i += 256) {
        sc += log(rowsum[i]);        // loss_i = log sum_j exp(logit_ij - logit_ii)
        sm += (double)magr[i];
    }
    for (int m = 1; m < 64; m <<= 1) {
        sc += __shfl_xor(sc, m, 64);
        sm += __shfl_xor(sm, m, 64);
    }
    __shared__ double red[4][2];
    const int wave = tid >> 6, lane = tid & 63;
    if (lane == 0) { red[wave][0] = sc; red[wave][1] = sm; }
    __syncthreads();
    if (tid == 0) {
        sc = red[0][0] + red[1][0] + red[2][0] + red[3][0];
        sm = red[0][1] + red[1][1] + red[2][1] + red[3][1];
        double lc = sc / (double)B_ROWS;
        double lm = sm / (double)B_ROWS;
        out[0] = (float)(0.5 * lc + 0.5 * lm);  // LOSS_SCALE=1, LAMBD=0.5
        out[1] = (float)lc;
        out[2] = (float)lm;
    }
}

extern "C" void kernel_launch(void* const* d_in, const int* in_sizes, int n_in,
                              void* d_out, int out_size, void* d_ws, size_t ws_size,
                              hipStream_t stream) {
    const float* P = (const float*)d_in[0];   // predicted [4096,768] fp32
    const float* T = (const float*)d_in[1];   // target    [4096,768] fp32
    float* out = (float*)d_out;               // 3 fp32 scalars

    char* ws = (char*)d_ws;
    double* rowsum = (double*)ws;               ws += B_ROWS * sizeof(double);
    float*  p_sq   = (float*)ws;                ws += B_ROWS * sizeof(float);
    float*  t_sq   = (float*)ws;                ws += B_ROWS * sizeof(float);
    float*  diagl  = (float*)ws;                ws += B_ROWS * sizeof(float);
    float*  magr   = (float*)ws;

    // rowsum must be zero each call (ws is re-poisoned to 0xAA before every launch)
    hipMemsetAsync(rowsum, 0, B_ROWS * sizeof(double), stream);

    rowstats_kernel<<<B_ROWS, 256, 0, stream>>>(P, T, p_sq, t_sq, diagl, magr);
    lse_gemm_kernel<<<dim3(B_ROWS / BN, B_ROWS / BM), 256, 0, stream>>>(
        P, T, p_sq, t_sq, diagl, rowsum);
    finalize_kernel<<<1, 256, 0, stream>>>(rowsum, magr, out);
}

// Round 2
// 133.726 us; speedup vs baseline: 1.1743x; 1.1743x over previous
//
#include <hip/hip_runtime.h>
#include <hip/hip_bf16.h>
#include <math.h>

// Problem constants (B=4096 rows, D=768 features)
#define B_ROWS 4096
#define D_DIM  768

#define BM 128
#define BN 128
#define BK 64          // 64 bf16 = 128 B per tile row = 8 x 16B chunks

typedef __attribute__((ext_vector_type(8))) short bf16x8;  // 8 bf16 = 4 VGPRs (MFMA A/B frag)
typedef __attribute__((ext_vector_type(4))) float f32x4;   // MFMA C/D frag

__device__ __forceinline__ unsigned short f32_to_bf16(float x) {
    // round-to-nearest-even; inputs are finite normals
    unsigned int u = __float_as_uint(x);
    return (unsigned short)((u + 0x7fffu + ((u >> 16) & 1u)) >> 16);
}

// async global->LDS, 16 B per lane. LDS dest is WAVE-UNIFORM base; HW writes
// lane L's 16 B at base + L*16 (m97/m104-verified semantics).
__device__ __forceinline__ void async_copy16(const unsigned short* g, unsigned short* l) {
    __builtin_amdgcn_global_load_lds(
        (const __attribute__((address_space(1))) unsigned int*)g,
        (__attribute__((address_space(3))) unsigned int*)l,
        16, 0, 0);
}

// K1: per-row stats + fp32->bf16 conversion. One WAVE per row (4 rows/block).
//   p_sq[i], t_sq[i], diagl[i] = exact fp32 diagonal logit, magr[i] = L1 ratio,
//   Pb/Tb = bf16 copies for MFMA staging, rowsum[i] = 0.
__global__ void __launch_bounds__(256) rowstats_kernel(
    const float* __restrict__ P, const float* __restrict__ T,
    unsigned short* __restrict__ Pb, unsigned short* __restrict__ Tb,
    float* __restrict__ p_sq, float* __restrict__ t_sq,
    float* __restrict__ diagl, float* __restrict__ magr,
    float* __restrict__ rowsum)
{
    const int wave = threadIdx.x >> 6, lane = threadIdx.x & 63;
    const int i = blockIdx.x * 4 + wave;
    const f32x4* prow = (const f32x4*)(P + (size_t)i * D_DIM);
    const f32x4* trow = (const f32x4*)(T + (size_t)i * D_DIM);
    ushort4* pbrow = (ushort4*)(Pb + (size_t)i * D_DIM);
    ushort4* tbrow = (ushort4*)(Tb + (size_t)i * D_DIM);

    float psq = 0.f, tsq = 0.f, cr = 0.f, l1 = 0.f, tm = 0.f;
    #pragma unroll
    for (int u = 0; u < 3; ++u) {         // 192 float4 per row / 64 lanes
        const int c4 = u * 64 + lane;
        f32x4 p = prow[c4], t = trow[c4];
        #pragma unroll
        for (int k = 0; k < 4; ++k) {
            psq += p[k] * p[k]; tsq += t[k] * t[k]; cr += p[k] * t[k];
            l1 += fabsf(p[k] - t[k]); tm += fabsf(t[k]);
        }
        pbrow[c4] = make_ushort4(f32_to_bf16(p[0]), f32_to_bf16(p[1]),
                                 f32_to_bf16(p[2]), f32_to_bf16(p[3]));
        tbrow[c4] = make_ushort4(f32_to_bf16(t[0]), f32_to_bf16(t[1]),
                                 f32_to_bf16(t[2]), f32_to_bf16(t[3]));
    }
    #pragma unroll
    for (int m = 1; m < 64; m <<= 1) {
        psq += __shfl_xor(psq, m, 64);
        tsq += __shfl_xor(tsq, m, 64);
        cr  += __shfl_xor(cr,  m, 64);
        l1  += __shfl_xor(l1,  m, 64);
        tm  += __shfl_xor(tm,  m, 64);
    }
    if (lane == 0) {
        p_sq[i] = psq;
        t_sq[i] = tsq;
        float sq = fmaxf(psq + tsq - 2.0f * cr, 0.0f);
        diagl[i] = -sqrtf(sq) * 10.0f;    // logit_ii = -dist/0.1 (the LSE shift)
        magr[i]  = l1 / tm;
        rowsum[i] = 0.0f;
    }
}

// K2: bf16-MFMA cross GEMM (128x128 tile) + shifted-exp row-sum epilogue.
// LDS layout: per tile row (128 B = 8 chunks of 16 B), chunk stored at
// slot (chunk ^ (row&7)) -> ds_read_b128 is 2-way-max on banks (free, m136).
// global_load_lds gathers the permuted chunks for free (per-lane global addr).
__global__ void __launch_bounds__(256) lse_gemm_kernel(
    const unsigned short* __restrict__ Pb, const unsigned short* __restrict__ Tb,
    const float* __restrict__ p_sq, const float* __restrict__ t_sq,
    const float* __restrict__ diagl, float* __restrict__ rowsum)
{
    __shared__ __align__(16) unsigned short As[BM * BK];  // 16 KB
    __shared__ __align__(16) unsigned short Bs[BN * BK];  // 16 KB

    const int tid = threadIdx.x;
    const int i0 = blockIdx.y * BM;   // P row block
    const int j0 = blockIdx.x * BN;   // T row block (= logit column block)

    const int lane  = tid & 63;
    const int wave  = tid >> 6;
    const int wm    = wave >> 1, wn = wave & 1;    // 2x2 wave grid
    const int row16 = lane & 15, quad = lane >> 4;
    const int m_base = wm * 64, n_base = wn * 64;

    // staging coords (fixed across kt): lane covers row (wave*32+it*8+lrow),
    // global chunk lchunk = (lane&7) ^ lrow  -> lands at LDS slot lane of group
    const int lrow   = lane >> 3;               // 0..7
    const int lchunk = (lane & 7) ^ lrow;       // swizzled chunk this lane fetches
    // ds_read swizzle: byte offset of (quad) chunk within a row, ks=0
    const int swz = (quad ^ (row16 & 7)) << 4;

    f32x4 acc[4][4];
    #pragma unroll
    for (int a = 0; a < 4; ++a)
        #pragma unroll
        for (int b = 0; b < 4; ++b)
            acc[a][b] = (f32x4){0.f, 0.f, 0.f, 0.f};

    const char* Ab = (const char*)As;
    const char* Bb = (const char*)Bs;

    for (int kt = 0; kt < D_DIM; kt += BK) {
        // Stage A and B tiles: 1024 slots x 16 B each, 4 wave-instrs per tile.
        #pragma unroll
        for (int it = 0; it < 4; ++it) {
            const int r = wave * 32 + it * 8 + lrow;
            async_copy16(Pb + (size_t)(i0 + r) * D_DIM + kt + lchunk * 8,
                         &As[(wave * 4 + it) * 512]);
        }
        #pragma unroll
        for (int it = 0; it < 4; ++it) {
            const int r = wave * 32 + it * 8 + lrow;
            async_copy16(Tb + (size_t)(j0 + r) * D_DIM + kt + lchunk * 8,
                         &Bs[(wave * 4 + it) * 512]);
        }
        __syncthreads();   // drains vmcnt (global_load_lds) before use

        #pragma unroll
        for (int ks = 0; ks < BK; ks += 32) {
            const int kx = ks ? 64 : 0;   // chunk+4 == slot^4 == byte addr^64
            bf16x8 a[4], b[4];
            #pragma unroll
            for (int mt = 0; mt < 4; ++mt) {
                const int off = (m_base + mt * 16 + row16) * 128 + swz;
                a[mt] = *(const bf16x8*)(Ab + (off ^ kx));
            }
            #pragma unroll
            for (int nt = 0; nt < 4; ++nt) {
                const int off = (n_base + nt * 16 + row16) * 128 + swz;
                b[nt] = *(const bf16x8*)(Bb + (off ^ kx));
            }
            #pragma unroll
            for (int mt = 0; mt < 4; ++mt)
                #pragma unroll
                for (int nt = 0; nt < 4; ++nt)
                    acc[mt][nt] = __builtin_amdgcn_mfma_f32_16x16x32_bf16(
                        a[mt], b[nt], acc[mt][nt], 0, 0, 0);
        }
        __syncthreads();
    }

    // Epilogue: C/D layout col=lane&15, row=quad*4+reg (m89/m91-verified).
    // loss term = exp(logit_ij - logit_ii); in log2 domain via exp2f.
    // Range: max shifted log2-exponent ~99 < 127 -> fp32 safe.
    const float NT_LOG2E = -14.4269504089f;   // -(1/TEMP) * log2(e)
    const float LOG2E    = 1.44269504089f;
    float tsq_l[4];
    #pragma unroll
    for (int nt = 0; nt < 4; ++nt)
        tsq_l[nt] = t_sq[j0 + n_base + nt * 16 + row16];

    #pragma unroll
    for (int mt = 0; mt < 4; ++mt) {
        #pragma unroll
        for (int r = 0; r < 4; ++r) {
            const int i = i0 + m_base + mt * 16 + quad * 4 + r;
            const float psq = p_sq[i];
            const float c0  = -diagl[i] * LOG2E;  // -logit_ii in log2 domain
            float s = 0.f;
            #pragma unroll
            for (int nt = 0; nt < 4; ++nt) {
                float c  = acc[mt][nt][r];
                float sq = fmaxf(fmaf(-2.0f, c, psq + tsq_l[nt]), 0.0f);
                float d  = sqrtf(sq);
                float y  = fmaf(d, NT_LOG2E, c0);  // (logit-logit_ii)*log2e
                s += exp2f(y);
            }
            #pragma unroll
            for (int m = 1; m < 16; m <<= 1) s += __shfl_xor(s, m, 64);
            if (row16 == 0) atomicAdd(&rowsum[i], s);
        }
    }
}

// K3: final reduction to the 3 output scalars.
__global__ void __launch_bounds__(256) finalize_kernel(
    const float* __restrict__ rowsum, const float* __restrict__ magr,
    float* __restrict__ out)
{
    const int tid = threadIdx.x;
    double sc = 0.0, sm = 0.0;
    for (int i = tid; i < B_ROWS; i += 256) {
        sc += log((double)rowsum[i]);   // loss_i = log sum_j exp(logit_ij - logit_ii)
        sm += (double)magr[i];
    }
    #pragma unroll
    for (int m = 1; m < 64; m <<= 1) {
        sc += __shfl_xor(sc, m, 64);
        sm += __shfl_xor(sm, m, 64);
    }
    __shared__ double red[4][2];
    const int wave = tid >> 6, lane = tid & 63;
    if (lane == 0) { red[wave][0] = sc; red[wave][1] = sm; }
    __syncthreads();
    if (tid == 0) {
        sc = red[0][0] + red[1][0] + red[2][0] + red[3][0];
        sm = red[0][1] + red[1][1] + red[2][1] + red[3][1];
        double lc = sc / (double)B_ROWS;
        double lm = sm / (double)B_ROWS;
        out[0] = (float)(0.5 * lc + 0.5 * lm);  // LOSS_SCALE=1, LAMBD=0.5
        out[1] = (float)lc;
        out[2] = (float)lm;
    }
}

extern "C" void kernel_launch(void* const* d_in, const int* in_sizes, int n_in,
                              void* d_out, int out_size, void* d_ws, size_t ws_size,
                              hipStream_t stream) {
    const float* P = (const float*)d_in[0];   // predicted [4096,768] fp32
    const float* T = (const float*)d_in[1];   // target    [4096,768] fp32
    float* out = (float*)d_out;               // 3 fp32 scalars

    char* ws = (char*)d_ws;
    float* rowsum = (float*)ws;               ws += B_ROWS * sizeof(float);
    float* p_sq   = (float*)ws;               ws += B_ROWS * sizeof(float);
    float* t_sq   = (float*)ws;               ws += B_ROWS * sizeof(float);
    float* diagl  = (float*)ws;               ws += B_ROWS * sizeof(float);
    float* magr   = (float*)ws;               ws += B_ROWS * sizeof(float);
    unsigned short* Pb = (unsigned short*)ws; ws += (size_t)B_ROWS * D_DIM * 2;
    unsigned short* Tb = (unsigned short*)ws;

    rowstats_kernel<<<B_ROWS / 4, 256, 0, stream>>>(
        P, T, Pb, Tb, p_sq, t_sq, diagl, magr, rowsum);
    lse_gemm_kernel<<<dim3(B_ROWS / BN, B_ROWS / BM), 256, 0, stream>>>(
        Pb, Tb, p_sq, t_sq, diagl, rowsum);
    finalize_kernel<<<1, 256, 0, stream>>>(rowsum, magr, out);
}

// Round 3
// 131.203 us; speedup vs baseline: 1.1969x; 1.0192x over previous
//
#include <hip/hip_runtime.h>
#include <hip/hip_bf16.h>
#include <math.h>

// Problem constants (B=4096 rows, D=768 features)
#define B_ROWS 4096
#define D_DIM  768

#define BM 128
#define BN 128
#define BK 64          // 64 bf16 = 128 B per tile row = 8 x 16B chunks
#define NKT (D_DIM / BK)   // 12 K-tiles

typedef __attribute__((ext_vector_type(8))) short bf16x8;  // 8 bf16 = 4 VGPRs (MFMA A/B frag)
typedef __attribute__((ext_vector_type(4))) float f32x4;   // MFMA C/D frag

__device__ __forceinline__ unsigned short f32_to_bf16(float x) {
    // round-to-nearest-even; inputs are finite normals
    unsigned int u = __float_as_uint(x);
    return (unsigned short)((u + 0x7fffu + ((u >> 16) & 1u)) >> 16);
}

// async global->LDS, 16 B per lane. LDS dest is WAVE-UNIFORM base; HW writes
// lane L's 16 B at base + L*16 (m97/m104-verified semantics).
__device__ __forceinline__ void async_copy16(const unsigned short* g, unsigned short* l) {
    __builtin_amdgcn_global_load_lds(
        (const __attribute__((address_space(1))) unsigned int*)g,
        (__attribute__((address_space(3))) unsigned int*)l,
        16, 0, 0);
}

// K1: per-row stats + fp32->bf16 conversion. One WAVE per row (4 rows/block).
__global__ void __launch_bounds__(256) rowstats_kernel(
    const float* __restrict__ P, const float* __restrict__ T,
    unsigned short* __restrict__ Pb, unsigned short* __restrict__ Tb,
    float* __restrict__ p_sq, float* __restrict__ t_sq,
    float* __restrict__ diagl, float* __restrict__ magr,
    float* __restrict__ rowsum)
{
    const int wave = threadIdx.x >> 6, lane = threadIdx.x & 63;
    const int i = blockIdx.x * 4 + wave;
    const f32x4* prow = (const f32x4*)(P + (size_t)i * D_DIM);
    const f32x4* trow = (const f32x4*)(T + (size_t)i * D_DIM);
    ushort4* pbrow = (ushort4*)(Pb + (size_t)i * D_DIM);
    ushort4* tbrow = (ushort4*)(Tb + (size_t)i * D_DIM);

    float psq = 0.f, tsq = 0.f, cr = 0.f, l1 = 0.f, tm = 0.f;
    #pragma unroll
    for (int u = 0; u < 3; ++u) {         // 192 float4 per row / 64 lanes
        const int c4 = u * 64 + lane;
        f32x4 p = prow[c4], t = trow[c4];
        #pragma unroll
        for (int k = 0; k < 4; ++k) {
            psq += p[k] * p[k]; tsq += t[k] * t[k]; cr += p[k] * t[k];
            l1 += fabsf(p[k] - t[k]); tm += fabsf(t[k]);
        }
        pbrow[c4] = make_ushort4(f32_to_bf16(p[0]), f32_to_bf16(p[1]),
                                 f32_to_bf16(p[2]), f32_to_bf16(p[3]));
        tbrow[c4] = make_ushort4(f32_to_bf16(t[0]), f32_to_bf16(t[1]),
                                 f32_to_bf16(t[2]), f32_to_bf16(t[3]));
    }
    #pragma unroll
    for (int m = 1; m < 64; m <<= 1) {
        psq += __shfl_xor(psq, m, 64);
        tsq += __shfl_xor(tsq, m, 64);
        cr  += __shfl_xor(cr,  m, 64);
        l1  += __shfl_xor(l1,  m, 64);
        tm  += __shfl_xor(tm,  m, 64);
    }
    if (lane == 0) {
        p_sq[i] = psq;
        t_sq[i] = tsq;
        float sq = fmaxf(psq + tsq - 2.0f * cr, 0.0f);
        diagl[i] = -sqrtf(sq) * 10.0f;    // logit_ii = -dist/0.1 (the LSE shift)
        magr[i]  = l1 / tm;
        rowsum[i] = 0.0f;
    }
}

// K2: bf16-MFMA cross GEMM (128x128 tile) + shifted-exp row-sum epilogue.
// Double-buffered LDS: prefetch of tile kt+1 is issued AFTER the barrier and
// BEFORE compute(kt), so the vmcnt(0) drain at the next barrier lands after a
// full compute phase (latency overlapped). One barrier per K-iter.
// LDS chunk-XOR swizzle (chunk ^ row&7, 16B granularity) -> 0 bank conflicts
// (verified R2), free at stage time via per-lane global addresses.
__global__ void __launch_bounds__(256) lse_gemm_kernel(
    const unsigned short* __restrict__ Pb, const unsigned short* __restrict__ Tb,
    const float* __restrict__ p_sq, const float* __restrict__ t_sq,
    const float* __restrict__ diagl, float* __restrict__ rowsum)
{
    __shared__ __align__(16) unsigned short As[2][BM * BK];  // 2 x 16 KB
    __shared__ __align__(16) unsigned short Bs[2][BN * BK];  // 2 x 16 KB

    const int tid = threadIdx.x;

    // XCD-aware swizzle: HW round-robins linear workgroup id over 8 XCDs
    // (flat%8). Group 8x8 tiles (3.1 MB working set < 4 MiB L2) onto one XCD.
    const int flat = blockIdx.y * (B_ROWS / BN) + blockIdx.x;
    const int xcd  = flat & 7;
    const int s    = flat >> 3;                 // 0..127: slot within XCD
    const int g    = xcd + ((s >> 6) << 3);     // group 0..15 (XCD-local pass 0/1)
    const int w    = s & 63;                    // tile within 8x8 group
    const int i0   = (((g >> 2) << 3) + (w >> 3)) * BM;  // P row block
    const int j0   = (((g & 3) << 3) + (w & 7)) * BN;    // T row block

    const int lane  = tid & 63;
    const int wave  = tid >> 6;
    const int wm    = wave >> 1, wn = wave & 1;    // 2x2 wave grid
    const int row16 = lane & 15, quad = lane >> 4;
    const int m_base = wm * 64, n_base = wn * 64;

    // staging coords: lane covers row (wave*32+it*8+lrow), swizzled chunk
    const int lrow   = lane >> 3;               // 0..7
    const int lchunk = (lane & 7) ^ lrow;       // chunk this lane fetches
    const int swz = (quad ^ (row16 & 7)) << 4;  // ds_read swizzled byte offset

    // per-lane global base (ushort units) for the staging loads
    const unsigned short* pg[4];
    const unsigned short* tg[4];
    #pragma unroll
    for (int it = 0; it < 4; ++it) {
        const int r = wave * 32 + it * 8 + lrow;
        pg[it] = Pb + (size_t)(i0 + r) * D_DIM + lchunk * 8;
        tg[it] = Tb + (size_t)(j0 + r) * D_DIM + lchunk * 8;
    }

    f32x4 acc[4][4];
    #pragma unroll
    for (int a = 0; a < 4; ++a)
        #pragma unroll
        for (int b = 0; b < 4; ++b)
            acc[a][b] = (f32x4){0.f, 0.f, 0.f, 0.f};

    // prologue: stage tile 0 into buffer 0
    #pragma unroll
    for (int it = 0; it < 4; ++it) {
        async_copy16(pg[it], &As[0][(wave * 4 + it) * 512]);
        async_copy16(tg[it], &Bs[0][(wave * 4 + it) * 512]);
    }

    for (int ktile = 0; ktile < NKT; ++ktile) {
        const int sel = ktile & 1;
        __syncthreads();   // drains vmcnt -> buffer sel is ready

        // prefetch next tile into the other buffer (latency hidden by compute)
        if (ktile + 1 < NKT) {
            const int kt1 = (ktile + 1) * BK;
            #pragma unroll
            for (int it = 0; it < 4; ++it) {
                async_copy16(pg[it] + kt1, &As[sel ^ 1][(wave * 4 + it) * 512]);
                async_copy16(tg[it] + kt1, &Bs[sel ^ 1][(wave * 4 + it) * 512]);
            }
        }

        const char* Ab = (const char*)As[sel];
        const char* Bb = (const char*)Bs[sel];
        #pragma unroll
        for (int ks = 0; ks < BK; ks += 32) {
            const int kx = ks ? 64 : 0;   // chunk+4 == chunk^4 == byte addr^64
            bf16x8 a[4], b[4];
            #pragma unroll
            for (int mt = 0; mt < 4; ++mt) {
                const int off = (m_base + mt * 16 + row16) * 128 + swz;
                a[mt] = *(const bf16x8*)(Ab + (off ^ kx));
            }
            #pragma unroll
            for (int nt = 0; nt < 4; ++nt) {
                const int off = (n_base + nt * 16 + row16) * 128 + swz;
                b[nt] = *(const bf16x8*)(Bb + (off ^ kx));
            }
            #pragma unroll
            for (int mt = 0; mt < 4; ++mt)
                #pragma unroll
                for (int nt = 0; nt < 4; ++nt)
                    acc[mt][nt] = __builtin_amdgcn_mfma_f32_16x16x32_bf16(
                        a[mt], b[nt], acc[mt][nt], 0, 0, 0);
        }
        // loop-top barrier guards buffer reuse (all waves finished reading sel)
    }

    // Epilogue: C/D layout col=lane&15, row=quad*4+reg (m89/m91-verified).
    // term = exp(logit_ij - logit_ii) via exp2f; max shifted log2-exp ~99 < 127.
    const float NT_LOG2E = -14.4269504089f;   // -(1/TEMP) * log2(e)
    const float LOG2E    = 1.44269504089f;
    float tsq_l[4];
    #pragma unroll
    for (int nt = 0; nt < 4; ++nt)
        tsq_l[nt] = t_sq[j0 + n_base + nt * 16 + row16];

    #pragma unroll
    for (int mt = 0; mt < 4; ++mt) {
        #pragma unroll
        for (int r = 0; r < 4; ++r) {
            const int i = i0 + m_base + mt * 16 + quad * 4 + r;
            const float psq = p_sq[i];
            const float c0  = -diagl[i] * LOG2E;  // -logit_ii in log2 domain
            float sfin = 0.f;
            #pragma unroll
            for (int nt = 0; nt < 4; ++nt) {
                float c  = acc[mt][nt][r];
                float sq = fmaxf(fmaf(-2.0f, c, psq + tsq_l[nt]), 0.0f);
                float d  = sqrtf(sq);
                float y  = fmaf(d, NT_LOG2E, c0);  // (logit-logit_ii)*log2e
                sfin += exp2f(y);
            }
            #pragma unroll
            for (int m = 1; m < 16; m <<= 1) sfin += __shfl_xor(sfin, m, 64);
            if (row16 == 0) atomicAdd(&rowsum[i], sfin);
        }
    }
}

// K3: final reduction to the 3 output scalars.
__global__ void __launch_bounds__(256) finalize_kernel(
    const float* __restrict__ rowsum, const float* __restrict__ magr,
    float* __restrict__ out)
{
    const int tid = threadIdx.x;
    double sc = 0.0, sm = 0.0;
    for (int i = tid; i < B_ROWS; i += 256) {
        sc += log((double)rowsum[i]);   // loss_i = log sum_j exp(logit_ij - logit_ii)
        sm += (double)magr[i];
    }
    #pragma unroll
    for (int m = 1; m < 64; m <<= 1) {
        sc += __shfl_xor(sc, m, 64);
        sm += __shfl_xor(sm, m, 64);
    }
    __shared__ double red[4][2];
    const int wave = tid >> 6, lane = tid & 63;
    if (lane == 0) { red[wave][0] = sc; red[wave][1] = sm; }
    __syncthreads();
    if (tid == 0) {
        sc = red[0][0] + red[1][0] + red[2][0] + red[3][0];
        sm = red[0][1] + red[1][1] + red[2][1] + red[3][1];
        double lc = sc / (double)B_ROWS;
        double lm = sm / (double)B_ROWS;
        out[0] = (float)(0.5 * lc + 0.5 * lm);  // LOSS_SCALE=1, LAMBD=0.5
        out[1] = (float)lc;
        out[2] = (float)lm;
    }
}

extern "C" void kernel_launch(void* const* d_in, const int* in_sizes, int n_in,
                              void* d_out, int out_size, void* d_ws, size_t ws_size,
                              hipStream_t stream) {
    const float* P = (const float*)d_in[0];   // predicted [4096,768] fp32
    const float* T = (const float*)d_in[1];   // target    [4096,768] fp32
    float* out = (float*)d_out;               // 3 fp32 scalars

    char* ws = (char*)d_ws;
    float* rowsum = (float*)ws;               ws += B_ROWS * sizeof(float);
    float* p_sq   = (float*)ws;               ws += B_ROWS * sizeof(float);
    float* t_sq   = (float*)ws;               ws += B_ROWS * sizeof(float);
    float* diagl  = (float*)ws;               ws += B_ROWS * sizeof(float);
    float* magr   = (float*)ws;               ws += B_ROWS * sizeof(float);
    unsigned short* Pb = (unsigned short*)ws; ws += (size_t)B_ROWS * D_DIM * 2;
    unsigned short* Tb = (unsigned short*)ws;

    rowstats_kernel<<<B_ROWS / 4, 256, 0, stream>>>(
        P, T, Pb, Tb, p_sq, t_sq, diagl, magr, rowsum);
    lse_gemm_kernel<<<dim3(B_ROWS / BN, B_ROWS / BM), 256, 0, stream>>>(
        Pb, Tb, p_sq, t_sq, diagl, rowsum);
    finalize_kernel<<<1, 256, 0, stream>>>(rowsum, magr, out);
}